// Round 5
// baseline (838.227 us; speedup 1.0000x reference)
//
#include <hip/hip_runtime.h>

typedef unsigned short u16;
typedef __attribute__((ext_vector_type(4))) unsigned short u16x4;
typedef __attribute__((ext_vector_type(8))) unsigned short u16x8;
typedef __attribute__((ext_vector_type(4))) short s16x4;
typedef __attribute__((ext_vector_type(4))) float f32x4;
typedef __attribute__((ext_vector_type(8))) __bf16 bf16x8;

__device__ __forceinline__ u16 f2bf(float f) {
  union { float f; unsigned int u; } v; v.f = f;
  unsigned int u = v.u;
  unsigned int r = (u + 0x7fffu + ((u >> 16) & 1u)) >> 16;
  return (u16)r;
}
__device__ __forceinline__ u16 f2bf_hw(float f) {  // RNE via HW convert
  return __builtin_bit_cast(u16, (__bf16)f);
}
__device__ __forceinline__ float bf2f(u16 h) {
  union { unsigned int u; float f; } v; v.u = ((unsigned int)h) << 16;
  return v.f;
}
__device__ __forceinline__ f32x4 mfma16(u16x8 a, u16x8 b, f32x4 c) {
  return __builtin_amdgcn_mfma_f32_16x16x32_bf16(
      __builtin_bit_cast(bf16x8, a), __builtin_bit_cast(bf16x8, b), c, 0, 0, 0);
}
// K=16 variant: A/B are 4 bf16 (2 VGPRs)
__device__ __forceinline__ f32x4 mfma16k16(u16x4 a, u16x4 b, f32x4 c) {
  return __builtin_amdgcn_mfma_f32_16x16x16bf16_1k(
      __builtin_bit_cast(s16x4, a), __builtin_bit_cast(s16x4, b), c, 0, 0, 0);
}
// async global->LDS, 16B per lane; LDS dest = wave-uniform base + lane*16
__device__ __forceinline__ void glds16(const void* g, void* l) {
  __builtin_amdgcn_global_load_lds((const __attribute__((address_space(1))) void*)g,
                                   (__attribute__((address_space(3))) void*)l, 16, 0, 0);
}

// ---------------- fp32 -> bf16 conversion ----------------
__global__ __launch_bounds__(256) void cvt_bf16(const float* __restrict__ x,
                                                u16* __restrict__ y, int n4) {
  int i = blockIdx.x * 256 + threadIdx.x;
  if (i >= n4) return;
  float4 v = ((const float4*)x)[i];
  u16x4 o;
  o.x = f2bf(v.x); o.y = f2bf(v.y); o.z = f2bf(v.z); o.w = f2bf(v.w);
  ((u16x4*)y)[i] = o;
}
__global__ __launch_bounds__(256) void cvt_w4(const float* __restrict__ a, const float* __restrict__ b,
                                              const float* __restrict__ c, const float* __restrict__ d,
                                              u16* __restrict__ oa, u16* __restrict__ ob,
                                              u16* __restrict__ oc, u16* __restrict__ od) {
  int w = blockIdx.y;
  const float* s = w == 0 ? a : w == 1 ? b : w == 2 ? c : d;
  u16* o = w == 0 ? oa : w == 1 ? ob : w == 2 ? oc : od;
  int i = blockIdx.x * 256 + threadIdx.x;
  float4 v = ((const float4*)s)[i];
  u16x4 r;
  r.x = f2bf(v.x); r.y = f2bf(v.y); r.z = f2bf(v.z); r.w = f2bf(v.w);
  ((u16x4*)o)[i] = r;
}

// ---------------- GEMM: C[M,1536] = A[M,1536] @ W[1536,1536]^T + bias ----------------
template <int OUT>  // 0 = bf16, 1 = f32, 2 = bf16 transposed (C^T[N][ldt])
__global__ __launch_bounds__(256, 2) void gemm_v2(
    const u16* __restrict__ A, const u16* __restrict__ W,
    const float* __restrict__ bias, void* __restrict__ Cp, int M, int ldt) {
  const int K = 1536, N = 1536;
  __shared__ __align__(16) u16 gsm[17408];
  u16* As = gsm;
  u16* Bs = gsm + 8192;
  const int tid = threadIdx.x;
  const int lane = tid & 63, wid = tid >> 6;
  const int quad = lane >> 4, l15 = lane & 15;
  const int m0 = blockIdx.y * 128, n0 = blockIdx.x * 128;
  const int wm = (wid >> 1) * 64, wn = (wid & 1) * 64;
  f32x4 acc[4][4];
#pragma unroll
  for (int i = 0; i < 4; ++i)
#pragma unroll
    for (int j = 0; j < 4; ++j)
#pragma unroll
      for (int r = 0; r < 4; ++r) acc[i][j][r] = 0.f;

  const int r8 = lane >> 3, c8 = lane & 7;
  const int gch = c8 ^ r8;

  for (int k0 = 0; k0 < K; k0 += 64) {
#pragma unroll
    for (int inst = 0; inst < 4; ++inst) {
      int row = wid * 32 + inst * 8 + r8;
      glds16(A + ((size_t)(m0 + row) * K + k0 + gch * 8), As + (wid * 32 + inst * 8) * 64);
      glds16(W + ((size_t)(n0 + row) * K + k0 + gch * 8), Bs + (wid * 32 + inst * 8) * 64);
    }
    asm volatile("s_waitcnt vmcnt(0)" ::: "memory");
    __syncthreads();
#pragma unroll
    for (int ks = 0; ks < 2; ++ks) {
      u16x8 af[4], bfr[4];
#pragma unroll
      for (int i = 0; i < 4; ++i) {
        int row = wm + i * 16 + l15;
        af[i] = *(const u16x8*)&As[row * 64 + (((ks * 4 + quad) ^ (l15 & 7)) * 8)];
      }
#pragma unroll
      for (int j = 0; j < 4; ++j) {
        int row = wn + j * 16 + l15;
        bfr[j] = *(const u16x8*)&Bs[row * 64 + (((ks * 4 + quad) ^ (l15 & 7)) * 8)];
      }
#pragma unroll
      for (int i = 0; i < 4; ++i)
#pragma unroll
        for (int j = 0; j < 4; ++j) acc[i][j] = mfma16(af[i], bfr[j], acc[i][j]);
    }
    __syncthreads();
  }

  if (OUT != 2) {
#pragma unroll
    for (int i = 0; i < 4; ++i) {
      int row = m0 + wm + i * 16 + quad * 4;
#pragma unroll
      for (int j = 0; j < 4; ++j) {
        int col = n0 + wn + j * 16 + l15;
        float bc = bias[col];
#pragma unroll
        for (int r = 0; r < 4; ++r) {
          if (row + r < M) {
            float v = acc[i][j][r] + bc;
            if (OUT == 1)
              ((float*)Cp)[(size_t)(row + r) * N + col] = v;
            else
              ((u16*)Cp)[(size_t)(row + r) * N + col] = f2bf(v);
          }
        }
      }
    }
  } else {
    u16* Ct = gsm;  // [128 n][136]
#pragma unroll
    for (int i = 0; i < 4; ++i)
#pragma unroll
      for (int j = 0; j < 4; ++j) {
        int nloc = wn + j * 16 + l15;
        float bc = bias[n0 + nloc];
#pragma unroll
        for (int r = 0; r < 4; ++r) {
          int mloc = wm + i * 16 + quad * 4 + r;
          Ct[nloc * 136 + mloc] = f2bf(acc[i][j][r] + bc);
        }
      }
    __syncthreads();
    int n = tid >> 1, half = tid & 1;
#pragma unroll
    for (int e = 0; e < 8; ++e) {
      int mloc = half * 64 + e * 8;
      if (m0 + mloc < M) {
        u16x8 v = *(const u16x8*)&Ct[n * 136 + mloc];
        *(u16x8*)((u16*)Cp + (size_t)(n0 + n) * ldt + m0 + mloc) = v;
      }
    }
  }
}

// ---------------- fused RMSNorm + interleaved RoPE, in-place bf16 ----------------
__global__ __launch_bounds__(192) void norm_rope2(u16* __restrict__ X,
                                                  const float* __restrict__ g,
                                                  const float* __restrict__ fc,
                                                  const float* __restrict__ fs,
                                                  float oscale) {
  const int DIMc = 1536;
  int row = blockIdx.x;
  int tid = threadIdx.x;
  u16* xr = X + (size_t)row * DIMc + tid * 8;
  u16x8 v = *(const u16x8*)xr;
  float x[8];
  float ss = 0.f;
#pragma unroll
  for (int e = 0; e < 8; ++e) { x[e] = bf2f(v[e]); ss += x[e] * x[e]; }
#pragma unroll
  for (int m = 1; m < 64; m <<= 1) ss += __shfl_xor(ss, m);
  __shared__ float w3[3];
  if ((tid & 63) == 0) w3[tid >> 6] = ss;
  __syncthreads();
  float rs = rsqrtf((w3[0] + w3[1] + w3[2]) * (1.f / 1536.f) + 1e-5f);
  int dhb = (tid * 8) & 127;
  const float* fcr = fc + (size_t)row * 128 + dhb;
  const float* fsr = fs + (size_t)row * 128 + dhb;
  float4 c0 = *(const float4*)fcr, c1 = *(const float4*)(fcr + 4);
  float4 s0 = *(const float4*)fsr, s1 = *(const float4*)(fsr + 4);
  const float* gp = g + tid * 8;
  float4 g0 = *(const float4*)gp, g1 = *(const float4*)(gp + 4);
  float cosv[4] = {c0.x, c0.z, c1.x, c1.z};
  float sinv[4] = {s0.y, s0.w, s1.y, s1.w};
  float gv[8] = {g0.x, g0.y, g0.z, g0.w, g1.x, g1.y, g1.z, g1.w};
  u16x8 o;
#pragma unroll
  for (int p = 0; p < 4; ++p) {
    float a = x[2 * p] * rs * gv[2 * p];
    float b = x[2 * p + 1] * rs * gv[2 * p + 1];
    o[2 * p] = f2bf((a * cosv[p] - b * sinv[p]) * oscale);
    o[2 * p + 1] = f2bf((a * sinv[p] + b * cosv[p]) * oscale);
  }
  *(u16x8*)xr = o;
}

// ---------------- block-sparse attention v9: 16-key chunks, conflict-free V ----------
// vs v8: (1) chunk shrinks 32->16 keys: LDS 32.5->16 KB per block -> 8 blocks/CU,
// 32 waves/CU (wave-slot capped); same LDS traffic per key (1 K-glds + 1 V-glds per
// wave per chunk, 4 b128 + 8 b64 reads). (2) V slot swizzle gains the (d>>2) row bit
// on BOTH stage-source and read addresses: bank = 16(d&1)+4slot+2(quad&1) now covers
// all 16 even b64 starts uniformly (4 accesses/bank = minimum) -> V reads conflict-free.
__global__ __launch_bounds__(256, 8) void attn9(
    const u16* __restrict__ Q, const u16* __restrict__ Kb,
    const u16* __restrict__ VT, const int* __restrict__ sel,
    float* __restrict__ Oacc, float* __restrict__ Lp) {
  const int HWc = 1560, DIMc = 1536, KTt = 12480, NT = 600;
  __shared__ __align__(16) u16 smem[8192];  // Ks0|Ks1|Vt0|Vt1, 4 KB each
  const int tid = threadIdx.x;
  const int lane = tid & 63, wid = tid >> 6;
  const int quad = lane >> 4, l15 = lane & 15;

  // XCD swizzle: all 100 blocks (4 segs x 25 q-tiles) of one (h,t) on one XCD.
  int bid = blockIdx.x;
  int xcd = bid & 7, slot = bid >> 3;
  int g = xcd + 8 * (slot / 100);
  int within = slot % 100;
  int seg = within / 25;
  int mt = within % 25;
  const int m0 = mt * 64;
  const int h = g >> 1, t = g & 1;
  const int tile = g * 25 + mt;  // 0..599

  int s0v = sel[2 * t];
  const int b0 = s0v > 0 ? s0v : 0;
  const int b1 = sel[2 * t + 1];
  const int nk = (b1 >= 0) ? 2 * HWc : HWc;
  const int nch = (nk + 15) >> 4;         // 16-key chunks
  const int cpseg = (nch + 3) >> 2;
  const int c0 = seg * cpseg;
  const int c1 = (c0 + cpseg < nch) ? c0 + cpseg : nch;

  // Q B-frags: this wave's 16 q rows
  u16x8 qf[4];
  {
    int qrow = m0 + wid * 16 + l15;
    if (qrow > HWc - 1) qrow = HWc - 1;
    const u16* qp = Q + (size_t)(t * HWc + qrow) * DIMc + h * 128;
#pragma unroll
    for (int ks = 0; ks < 4; ++ks) qf[ks] = *(const u16x8*)(qp + ks * 32 + quad * 8);
  }

  f32x4 oacc[8];  // partial O^T for this wave's 16 q: [d-tile]
#pragma unroll
  for (int m = 0; m < 8; ++m)
#pragma unroll
    for (int r = 0; r < 4; ++r) oacc[m][r] = 0.f;
  float lp = 0.f;

  auto stage = [&](int kc, int buf) {
    u16* Ks = smem + buf * 2048;
    u16* Vt = smem + 4096 + buf * 2048;
    // K: 16 rows x 128 u16 (256B). Wave w stages rows w*4..+4 (1 glds).
    // LDS slot s of row r holds col-group s^r (matches read swizzle).
    {
      int kl = wid * 4 + (lane >> 4);
      int gc = (lane & 15) ^ kl;
      int kg = kc + kl;
      if (kg >= nk) kg = 0;
      int big = kg >= HWc;
      int tok = (big ? b1 : b0) * HWc + kg - (big ? HWc : 0);
      glds16(Kb + ((size_t)tok * DIMc + h * 128 + gc * 8), Ks + (wid * 4) * 128);
    }
    // V^T: 128 d rows x 16 u16 (32B). Wave w stages d rows w*32..+32 (1 glds, 2 lanes/row).
    // LDS slot s of row d holds key-group s ^ ((d>>2)&1) -> conflict-free read banks.
    {
      int dl = wid * 32 + (lane >> 1);
      int gc = (lane & 1) ^ ((dl >> 2) & 1);
      int tg = kc + gc * 8;
      if (tg >= nk) tg = 0;
      int big = tg >= HWc;
      int tok = (big ? b1 : b0) * HWc + tg - (big ? HWc : 0);
      glds16(VT + ((size_t)(h * 128 + dl) * KTt + tok), Vt + (wid * 32) * 16);
    }
  };

  if (c0 < c1) stage(c0 * 16, 0);

  for (int c = c0; c < c1; ++c) {
    const int buf = (c - c0) & 1;
    u16* Ks = smem + buf * 2048;
    u16* Vt = smem + 4096 + buf * 2048;
    asm volatile("s_waitcnt vmcnt(0)\n\ts_barrier" ::: "memory");
    if (c + 1 < c1) stage((c + 1) * 16, buf ^ 1);

    // S^T = K Q^T: 16 keys x this wave's 16 q
    f32x4 s;
#pragma unroll
    for (int r = 0; r < 4; ++r) s[r] = 0.f;
#pragma unroll
    for (int ks = 0; ks < 4; ++ks) {
      u16x8 ka = *(const u16x8*)&Ks[l15 * 128 + (((ks * 4 + quad) ^ l15) * 8)];
      s = mfma16(ka, qf[ks], s);
    }

    // p = 2^s (one-pass softmax); mask only the final (partial) chunk
    float p[4];
#pragma unroll
    for (int r = 0; r < 4; ++r) p[r] = exp2f(s[r]);
    if ((c + 1) * 16 > nk) {  // wave-uniform
#pragma unroll
      for (int r = 0; r < 4; ++r)
        if (c * 16 + quad * 4 + r >= nk) p[r] = 0.f;
    }
    u16x4 pb;
#pragma unroll
    for (int r = 0; r < 4; ++r) {
      lp += p[r];
      pb[r] = f2bf_hw(p[r]);
    }

    // partial O^T += V^T · P^T: K=16 mfma, B straight from S^T C-frags
#pragma unroll
    for (int m = 0; m < 8; ++m) {
      int d = m * 16 + l15;
      u16x4 va = *(const u16x4*)&Vt[d * 16 + ((((quad >> 1) ^ ((d >> 2) & 1)) * 8)) + (quad & 1) * 4];
      oacc[m] = mfma16k16(va, pb, oacc[m]);
    }
  }

  // denominator: reduce over quads (keys); every lane ends with its q-row sum
  lp += __shfl_xor(lp, 16);
  lp += __shfl_xor(lp, 32);
  const size_t sbase = ((size_t)seg * NT + tile) * 64 + wid * 16;
  if (lane < 16) Lp[sbase + lane] = lp;
#pragma unroll
  for (int m = 0; m < 8; ++m)
    *(f32x4*)&Oacc[(sbase + l15) * 128 + m * 16 + quad * 4] = oacc[m];
}

// ---------------- normalize: O = bf16(sum_seg Oacc / sum_seg Lp) ----------------
__global__ __launch_bounds__(256) void attn_norm(const float* __restrict__ Oacc,
                                                 const float* __restrict__ Lp,
                                                 u16* __restrict__ O) {
  const int HWc = 1560, DIMc = 1536, NT = 600;
  int tile = blockIdx.x;  // 600
  int g = tile / 25, mt = tile % 25;
  int h = g >> 1, t = g & 1;
  int m0 = mt * 64;
  int tid = threadIdx.x;
#pragma unroll
  for (int e = 0; e < 8; ++e) {
    int idx = e * 256 + tid;   // 0..2047 f32x4 slots (64 q x 32)
    int qloc = idx >> 5;
    int d4 = (idx & 31) * 4;
    int q = m0 + qloc;
    if (q < HWc) {
      f32x4 a = {0.f, 0.f, 0.f, 0.f};
      float l = 0.f;
#pragma unroll
      for (int s = 0; s < 4; ++s) {
        const size_t sbase = ((size_t)s * NT + tile) * 64 + qloc;
        f32x4 v = *(const f32x4*)&Oacc[sbase * 128 + d4];
#pragma unroll
        for (int r = 0; r < 4; ++r) a[r] += v[r];
        l += Lp[sbase];
      }
      float linv = 1.f / l;
      u16x4 o;
#pragma unroll
      for (int r = 0; r < 4; ++r) o[r] = f2bf(a[r] * linv);
      *(u16x4*)(O + (size_t)(t * HWc + q) * DIMc + h * 128 + d4) = o;
    }
  }
}

extern "C" void kernel_launch(void* const* d_in, const int* in_sizes, int n_in,
                              void* d_out, int out_size, void* d_ws, size_t ws_size,
                              hipStream_t stream) {
  const float* hs  = (const float*)d_in[0];
  const float* his = (const float*)d_in[1];
  const float* fc  = (const float*)d_in[2];
  const float* fs  = (const float*)d_in[3];
  const float* fch = (const float*)d_in[4];
  const float* fsh = (const float*)d_in[5];
  const int*   sel = (const int*)d_in[6];
  const float* Wq  = (const float*)d_in[7];
  const float* bq  = (const float*)d_in[8];
  const float* Wk  = (const float*)d_in[9];
  const float* bk  = (const float*)d_in[10];
  const float* Wv  = (const float*)d_in[11];
  const float* bv  = (const float*)d_in[12];
  const float* Wo  = (const float*)d_in[13];
  const float* bo  = (const float*)d_in[14];
  const float* gq  = (const float*)d_in[15];
  const float* gk  = (const float*)d_in[16];

  const int QT = 3120, KT = 12480, DIMc = 1536;
  // Live-through-attention buffers first; the bf16 staging buffers (dead once the
  // gemms have consumed them) are overlaid with the 79.2 MB f32 segment partials.
  u16* p = (u16*)d_ws;
  u16* qb  = p; p += (size_t)QT * DIMc;
  u16* kb2 = p; p += (size_t)KT * DIMc;
  u16* vt  = p; p += (size_t)DIMc * KT;   // V^T [1536][12480]
  u16* ab  = p; p += (size_t)QT * DIMc;
  u16* wob = p; p += (size_t)DIMc * DIMc;
  u16* scratch = p;
  u16* hsb = scratch;
  u16* hib = hsb + (size_t)QT * DIMc;
  u16* wqb = hib + (size_t)KT * DIMc;
  u16* wkb = wqb + (size_t)DIMc * DIMc;
  u16* wvb = wkb + (size_t)DIMc * DIMc;
  float* oaccb = (float*)scratch;                      // f32 [4][600][64][128]
  float* lpb   = oaccb + (size_t)4 * 600 * 64 * 128;   // f32 [4][600][64]

  cvt_bf16<<<dim3((QT * DIMc / 4 + 255) / 256), 256, 0, stream>>>(hs, hsb, QT * DIMc / 4);
  cvt_bf16<<<dim3((KT * DIMc / 4 + 255) / 256), 256, 0, stream>>>(his, hib, KT * DIMc / 4);
  cvt_w4<<<dim3(2304, 4), 256, 0, stream>>>(Wq, Wk, Wv, Wo, wqb, wkb, wvb, wob);

  gemm_v2<0><<<dim3(12, 25), 256, 0, stream>>>(hsb, wqb, bq, qb, QT, 0);
  gemm_v2<0><<<dim3(12, 98), 256, 0, stream>>>(hib, wkb, bk, kb2, KT, 0);
  gemm_v2<2><<<dim3(12, 98), 256, 0, stream>>>(hib, wvb, bv, vt, KT, KT);  // writes V^T

  const float qscale = (float)(0.08838834764831845 * 1.4426950408889634);
  norm_rope2<<<dim3(QT), 192, 0, stream>>>(qb, gq, fc, fs, qscale);
  norm_rope2<<<dim3(KT), 192, 0, stream>>>(kb2, gk, fch, fsh, 1.0f);

  // attn9 clobbers hsb/hib/wq/wk/wv (all dead by now); wob stays live for the final gemm.
  attn9<<<dim3(2400), 256, 0, stream>>>(qb, kb2, vt, sel, oaccb, lpb);
  attn_norm<<<dim3(600), 256, 0, stream>>>(oaccb, lpb, ab);

  gemm_v2<1><<<dim3(12, 25), 256, 0, stream>>>(ab, wob, bo, d_out, QT, 0);
}

// Round 6
// 581.793 us; speedup vs baseline: 1.4408x; 1.4408x over previous
//
#include <hip/hip_runtime.h>

typedef unsigned short u16;
typedef __attribute__((ext_vector_type(4))) unsigned short u16x4;
typedef __attribute__((ext_vector_type(8))) unsigned short u16x8;
typedef __attribute__((ext_vector_type(4))) short s16x4;
typedef __attribute__((ext_vector_type(4))) float f32x4;
typedef __attribute__((ext_vector_type(8))) __bf16 bf16x8;

__device__ __forceinline__ u16 f2bf(float f) {
  union { float f; unsigned int u; } v; v.f = f;
  unsigned int u = v.u;
  unsigned int r = (u + 0x7fffu + ((u >> 16) & 1u)) >> 16;
  return (u16)r;
}
__device__ __forceinline__ u16 f2bf_hw(float f) {  // RNE via HW convert
  return __builtin_bit_cast(u16, (__bf16)f);
}
__device__ __forceinline__ float bf2f(u16 h) {
  union { unsigned int u; float f; } v; v.u = ((unsigned int)h) << 16;
  return v.f;
}
__device__ __forceinline__ f32x4 mfma16(u16x8 a, u16x8 b, f32x4 c) {
  return __builtin_amdgcn_mfma_f32_16x16x32_bf16(
      __builtin_bit_cast(bf16x8, a), __builtin_bit_cast(bf16x8, b), c, 0, 0, 0);
}
// K=16 variant: A/B are 4 bf16 (2 VGPRs)
__device__ __forceinline__ f32x4 mfma16k16(u16x4 a, u16x4 b, f32x4 c) {
  return __builtin_amdgcn_mfma_f32_16x16x16bf16_1k(
      __builtin_bit_cast(s16x4, a), __builtin_bit_cast(s16x4, b), c, 0, 0, 0);
}
// async global->LDS, 16B per lane; LDS dest = wave-uniform base + lane*16
__device__ __forceinline__ void glds16(const void* g, void* l) {
  __builtin_amdgcn_global_load_lds((const __attribute__((address_space(1))) void*)g,
                                   (__attribute__((address_space(3))) void*)l, 16, 0, 0);
}

// ---------------- fp32 -> bf16 conversion ----------------
__global__ __launch_bounds__(256) void cvt_bf16(const float* __restrict__ x,
                                                u16* __restrict__ y, int n4) {
  int i = blockIdx.x * 256 + threadIdx.x;
  if (i >= n4) return;
  float4 v = ((const float4*)x)[i];
  u16x4 o;
  o.x = f2bf(v.x); o.y = f2bf(v.y); o.z = f2bf(v.z); o.w = f2bf(v.w);
  ((u16x4*)y)[i] = o;
}
__global__ __launch_bounds__(256) void cvt_w4(const float* __restrict__ a, const float* __restrict__ b,
                                              const float* __restrict__ c, const float* __restrict__ d,
                                              u16* __restrict__ oa, u16* __restrict__ ob,
                                              u16* __restrict__ oc, u16* __restrict__ od) {
  int w = blockIdx.y;
  const float* s = w == 0 ? a : w == 1 ? b : w == 2 ? c : d;
  u16* o = w == 0 ? oa : w == 1 ? ob : w == 2 ? oc : od;
  int i = blockIdx.x * 256 + threadIdx.x;
  float4 v = ((const float4*)s)[i];
  u16x4 r;
  r.x = f2bf(v.x); r.y = f2bf(v.y); r.z = f2bf(v.z); r.w = f2bf(v.w);
  ((u16x4*)o)[i] = r;
}

// ---------------- GEMM: C[M,1536] = A[M,1536] @ W[1536,1536]^T + bias ----------------
template <int OUT>  // 0 = bf16, 1 = f32, 2 = bf16 transposed (C^T[N][ldt])
__global__ __launch_bounds__(256, 2) void gemm_v2(
    const u16* __restrict__ A, const u16* __restrict__ W,
    const float* __restrict__ bias, void* __restrict__ Cp, int M, int ldt) {
  const int K = 1536, N = 1536;
  __shared__ __align__(16) u16 gsm[17408];
  u16* As = gsm;
  u16* Bs = gsm + 8192;
  const int tid = threadIdx.x;
  const int lane = tid & 63, wid = tid >> 6;
  const int quad = lane >> 4, l15 = lane & 15;
  const int m0 = blockIdx.y * 128, n0 = blockIdx.x * 128;
  const int wm = (wid >> 1) * 64, wn = (wid & 1) * 64;
  f32x4 acc[4][4];
#pragma unroll
  for (int i = 0; i < 4; ++i)
#pragma unroll
    for (int j = 0; j < 4; ++j)
#pragma unroll
      for (int r = 0; r < 4; ++r) acc[i][j][r] = 0.f;

  const int r8 = lane >> 3, c8 = lane & 7;
  const int gch = c8 ^ r8;

  for (int k0 = 0; k0 < K; k0 += 64) {
#pragma unroll
    for (int inst = 0; inst < 4; ++inst) {
      int row = wid * 32 + inst * 8 + r8;
      glds16(A + ((size_t)(m0 + row) * K + k0 + gch * 8), As + (wid * 32 + inst * 8) * 64);
      glds16(W + ((size_t)(n0 + row) * K + k0 + gch * 8), Bs + (wid * 32 + inst * 8) * 64);
    }
    asm volatile("s_waitcnt vmcnt(0)" ::: "memory");
    __syncthreads();
#pragma unroll
    for (int ks = 0; ks < 2; ++ks) {
      u16x8 af[4], bfr[4];
#pragma unroll
      for (int i = 0; i < 4; ++i) {
        int row = wm + i * 16 + l15;
        af[i] = *(const u16x8*)&As[row * 64 + (((ks * 4 + quad) ^ (l15 & 7)) * 8)];
      }
#pragma unroll
      for (int j = 0; j < 4; ++j) {
        int row = wn + j * 16 + l15;
        bfr[j] = *(const u16x8*)&Bs[row * 64 + (((ks * 4 + quad) ^ (l15 & 7)) * 8)];
      }
#pragma unroll
      for (int i = 0; i < 4; ++i)
#pragma unroll
        for (int j = 0; j < 4; ++j) acc[i][j] = mfma16(af[i], bfr[j], acc[i][j]);
    }
    __syncthreads();
  }

  if (OUT != 2) {
#pragma unroll
    for (int i = 0; i < 4; ++i) {
      int row = m0 + wm + i * 16 + quad * 4;
#pragma unroll
      for (int j = 0; j < 4; ++j) {
        int col = n0 + wn + j * 16 + l15;
        float bc = bias[col];
#pragma unroll
        for (int r = 0; r < 4; ++r) {
          if (row + r < M) {
            float v = acc[i][j][r] + bc;
            if (OUT == 1)
              ((float*)Cp)[(size_t)(row + r) * N + col] = v;
            else
              ((u16*)Cp)[(size_t)(row + r) * N + col] = f2bf(v);
          }
        }
      }
    }
  } else {
    u16* Ct = gsm;  // [128 n][136]
#pragma unroll
    for (int i = 0; i < 4; ++i)
#pragma unroll
      for (int j = 0; j < 4; ++j) {
        int nloc = wn + j * 16 + l15;
        float bc = bias[n0 + nloc];
#pragma unroll
        for (int r = 0; r < 4; ++r) {
          int mloc = wm + i * 16 + quad * 4 + r;
          Ct[nloc * 136 + mloc] = f2bf(acc[i][j][r] + bc);
        }
      }
    __syncthreads();
    int n = tid >> 1, half = tid & 1;
#pragma unroll
    for (int e = 0; e < 8; ++e) {
      int mloc = half * 64 + e * 8;
      if (m0 + mloc < M) {
        u16x8 v = *(const u16x8*)&Ct[n * 136 + mloc];
        *(u16x8*)((u16*)Cp + (size_t)(n0 + n) * ldt + m0 + mloc) = v;
      }
    }
  }
}

// ---------------- fused RMSNorm + interleaved RoPE, in-place bf16 ----------------
__global__ __launch_bounds__(192) void norm_rope2(u16* __restrict__ X,
                                                  const float* __restrict__ g,
                                                  const float* __restrict__ fc,
                                                  const float* __restrict__ fs,
                                                  float oscale) {
  const int DIMc = 1536;
  int row = blockIdx.x;
  int tid = threadIdx.x;
  u16* xr = X + (size_t)row * DIMc + tid * 8;
  u16x8 v = *(const u16x8*)xr;
  float x[8];
  float ss = 0.f;
#pragma unroll
  for (int e = 0; e < 8; ++e) { x[e] = bf2f(v[e]); ss += x[e] * x[e]; }
#pragma unroll
  for (int m = 1; m < 64; m <<= 1) ss += __shfl_xor(ss, m);
  __shared__ float w3[3];
  if ((tid & 63) == 0) w3[tid >> 6] = ss;
  __syncthreads();
  float rs = rsqrtf((w3[0] + w3[1] + w3[2]) * (1.f / 1536.f) + 1e-5f);
  int dhb = (tid * 8) & 127;
  const float* fcr = fc + (size_t)row * 128 + dhb;
  const float* fsr = fs + (size_t)row * 128 + dhb;
  float4 c0 = *(const float4*)fcr, c1 = *(const float4*)(fcr + 4);
  float4 s0 = *(const float4*)fsr, s1 = *(const float4*)(fsr + 4);
  const float* gp = g + tid * 8;
  float4 g0 = *(const float4*)gp, g1 = *(const float4*)(gp + 4);
  float cosv[4] = {c0.x, c0.z, c1.x, c1.z};
  float sinv[4] = {s0.y, s0.w, s1.y, s1.w};
  float gv[8] = {g0.x, g0.y, g0.z, g0.w, g1.x, g1.y, g1.z, g1.w};
  u16x8 o;
#pragma unroll
  for (int p = 0; p < 4; ++p) {
    float a = x[2 * p] * rs * gv[2 * p];
    float b = x[2 * p + 1] * rs * gv[2 * p + 1];
    o[2 * p] = f2bf((a * cosv[p] - b * sinv[p]) * oscale);
    o[2 * p + 1] = f2bf((a * sinv[p] + b * cosv[p]) * oscale);
  }
  *(u16x8*)xr = o;
}

// ---------------- block-sparse attention v10: 128-q macro-tile, conflict-free V ------
// Back to attn8's L2-friendly operating point (32-key chunks, ~4 blocks/CU resident,
// FETCH ~20 MB), with its two measured costs fixed:
//  (1) LDS pipe load halved: 4 waves x 32 q rows each (128-q macro tile). K/V frags
//      are read once per wave per chunk and reused for both q sub-tiles, so LDS reads
//      per chunk (64 KB/block) now serve 128q x 32k instead of 64q x 32k.
//  (2) V-read bank conflicts (33.9M cyc in v8): slot swizzle gains the ((d>>2)&3)
//      row bits on BOTH stage-source and read -> <=2 lanes/bank (free).
__global__ __launch_bounds__(256, 3) void attn10(
    const u16* __restrict__ Q, const u16* __restrict__ Kb,
    const u16* __restrict__ VT, const int* __restrict__ sel,
    float* __restrict__ Oacc, float* __restrict__ Lp) {
  const int HWc = 1560, DIMc = 1536, KTt = 12480, NT = 600;
  __shared__ __align__(16) u16 smem[16384];  // Ks0|Ks1|Vt0|Vt1 (8 KB each)
  const int tid = threadIdx.x;
  const int lane = tid & 63, wid = tid >> 6;
  const int quad = lane >> 4, l15 = lane & 15;

  // XCD swizzle: all 52 blocks (4 segs x 13 macro-tiles) of one (h,t) on one XCD;
  // consecutive slots share a segment's K/V quarter (L2 locality).
  int bid = blockIdx.x;
  int xcd = bid & 7, slot = bid >> 3;
  int g = xcd + 8 * (slot / 52);
  int within = slot % 52;
  int seg = within / 13;
  int mt = within % 13;
  const int m0 = mt * 128;
  const int h = g >> 1, t = g & 1;

  int s0v = sel[2 * t];
  const int b0 = s0v > 0 ? s0v : 0;
  const int b1 = sel[2 * t + 1];
  const int nk = (b1 >= 0) ? 2 * HWc : HWc;
  const int nch = (nk + 31) >> 5;
  const int cpseg = (nch + 3) >> 2;
  const int c0 = seg * cpseg;
  const int c1 = (c0 + cpseg < nch) ? c0 + cpseg : nch;

  // Q B-frags: this wave's 32 q rows (2 sub-tiles of 16)
  u16x8 qf[2][4];
#pragma unroll
  for (int qt = 0; qt < 2; ++qt) {
    int qrow = m0 + wid * 32 + qt * 16 + l15;
    if (qrow > HWc - 1) qrow = HWc - 1;
    const u16* qp = Q + (size_t)(t * HWc + qrow) * DIMc + h * 128;
#pragma unroll
    for (int ks = 0; ks < 4; ++ks) qf[qt][ks] = *(const u16x8*)(qp + ks * 32 + quad * 8);
  }

  f32x4 oacc[2][8];  // partial O^T: [q-subtile][d-tile]
#pragma unroll
  for (int qt = 0; qt < 2; ++qt)
#pragma unroll
    for (int m = 0; m < 8; ++m)
#pragma unroll
      for (int r = 0; r < 4; ++r) oacc[qt][m][r] = 0.f;
  float lp[2] = {0.f, 0.f};

  auto stage = [&](int kc, int buf) {
    u16* Ks = smem + buf * 4096;
    u16* Vt = smem + 8192 + buf * 4096;
    // K: 32 rows x 128 u16; wave w stages rows w*8..+8 (2 glds, 4 rows each).
    // LDS slot s of row r holds col-group s^(r&15) (matches read swizzle).
#pragma unroll
    for (int n = 0; n < 2; ++n) {
      int kl = wid * 8 + n * 4 + (lane >> 4);
      int gc = (lane & 15) ^ (kl & 15);
      int kg = kc + kl;
      if (kg >= nk) kg = 0;
      int big = kg >= HWc;
      int tok = (big ? b1 : b0) * HWc + kg - (big ? HWc : 0);
      glds16(Kb + ((size_t)tok * DIMc + h * 128 + gc * 8), Ks + (wid * 8 + n * 4) * 128);
    }
    // V^T: 128 d rows x 32 u16 (64B); wave w stages d rows w*32..+32 (2 glds, 16 rows).
    // LDS slot s of row d holds key-group s ^ (d&3) ^ ((d>>2)&3) -> conflict-free reads.
#pragma unroll
    for (int n = 0; n < 2; ++n) {
      int dl = wid * 32 + n * 16 + (lane >> 2);
      int gc = (lane & 3) ^ (dl & 3) ^ ((dl >> 2) & 3);
      int tg = kc + gc * 8;
      if (tg >= nk) tg = 0;
      int big = tg >= HWc;
      int tok = (big ? b1 : b0) * HWc + tg - (big ? HWc : 0);
      glds16(VT + ((size_t)(h * 128 + dl) * KTt + tok), Vt + (wid * 32 + n * 16) * 32);
    }
  };

  if (c0 < c1) stage(c0 * 32, 0);

  for (int c = c0; c < c1; ++c) {
    const int buf = (c - c0) & 1;
    u16* Ks = smem + buf * 4096;
    u16* Vt = smem + 8192 + buf * 4096;
    asm volatile("s_waitcnt vmcnt(0)\n\ts_barrier" ::: "memory");
    if (c + 1 < c1) stage((c + 1) * 32, buf ^ 1);

    // S^T = K Q^T: 32 keys x this wave's 32 q (two 16-key groups x two q sub-tiles)
    f32x4 s[2][2];  // [gg][qt]
#pragma unroll
    for (int gg = 0; gg < 2; ++gg)
#pragma unroll
      for (int qt = 0; qt < 2; ++qt)
#pragma unroll
        for (int r = 0; r < 4; ++r) s[gg][qt][r] = 0.f;
#pragma unroll
    for (int ks = 0; ks < 4; ++ks)
#pragma unroll
      for (int gg = 0; gg < 2; ++gg) {
        u16x8 ka = *(const u16x8*)&Ks[(gg * 16 + l15) * 128 + (((ks * 4 + quad) ^ l15) * 8)];
#pragma unroll
        for (int qt = 0; qt < 2; ++qt) s[gg][qt] = mfma16(ka, qf[qt][ks], s[gg][qt]);
      }

    // p = 2^s (one-pass softmax); mask only the final (partial) chunk
    float p[2][2][4];
#pragma unroll
    for (int gg = 0; gg < 2; ++gg)
#pragma unroll
      for (int qt = 0; qt < 2; ++qt)
#pragma unroll
        for (int r = 0; r < 4; ++r) p[gg][qt][r] = exp2f(s[gg][qt][r]);
    if ((c + 1) * 32 > nk) {  // wave-uniform
#pragma unroll
      for (int gg = 0; gg < 2; ++gg)
#pragma unroll
        for (int r = 0; r < 4; ++r) {
          bool bad = c * 32 + gg * 16 + quad * 4 + r >= nk;
          if (bad) {
#pragma unroll
            for (int qt = 0; qt < 2; ++qt) p[gg][qt][r] = 0.f;
          }
        }
    }
    u16x4 pb[2][2];
#pragma unroll
    for (int gg = 0; gg < 2; ++gg)
#pragma unroll
      for (int qt = 0; qt < 2; ++qt)
#pragma unroll
        for (int r = 0; r < 4; ++r) {
          lp[qt] += p[gg][qt][r];
          pb[gg][qt][r] = f2bf_hw(p[gg][qt][r]);
        }

    // partial O^T += V^T · P^T: K=16 mfma, B straight from S^T C-frags;
    // each va fragment reused for both q sub-tiles.
#pragma unroll
    for (int m = 0; m < 8; ++m) {
      int d = m * 16 + l15;
#pragma unroll
      for (int gg = 0; gg < 2; ++gg) {
        int sl = (gg * 2 + (quad >> 1)) ^ (d & 3) ^ ((d >> 2) & 3);
        u16x4 va = *(const u16x4*)&Vt[d * 32 + sl * 8 + (quad & 1) * 4];
#pragma unroll
        for (int qt = 0; qt < 2; ++qt) oacc[qt][m] = mfma16k16(va, pb[gg][qt], oacc[qt][m]);
      }
    }
  }

  // denominator: reduce over quads (keys); every lane ends with its q-row sum
#pragma unroll
  for (int qt = 0; qt < 2; ++qt) {
    lp[qt] += __shfl_xor(lp[qt], 16);
    lp[qt] += __shfl_xor(lp[qt], 32);
  }
  // store into [seg][600 old-tiles][64][128] layout (old tile = 64 q rows)
#pragma unroll
  for (int qt = 0; qt < 2; ++qt) {
    int qrow0 = m0 + wid * 32 + qt * 16;  // wave-uniform
    if (qrow0 < HWc) {
      size_t sb = ((size_t)seg * NT + g * 25 + (qrow0 >> 6)) * 64 + (qrow0 & 63);
      if (lane < 16 && qrow0 + lane < HWc) Lp[sb + lane] = lp[qt];
      if (qrow0 + l15 < HWc) {
#pragma unroll
        for (int m = 0; m < 8; ++m)
          *(f32x4*)&Oacc[(sb + l15) * 128 + m * 16 + quad * 4] = oacc[qt][m];
      }
    }
  }
}

// ---------------- normalize: O = bf16(sum_seg Oacc / sum_seg Lp) ----------------
__global__ __launch_bounds__(256) void attn_norm(const float* __restrict__ Oacc,
                                                 const float* __restrict__ Lp,
                                                 u16* __restrict__ O) {
  const int HWc = 1560, DIMc = 1536, NT = 600;
  int tile = blockIdx.x;  // 600
  int g = tile / 25, mt = tile % 25;
  int h = g >> 1, t = g & 1;
  int m0 = mt * 64;
  int tid = threadIdx.x;
#pragma unroll
  for (int e = 0; e < 8; ++e) {
    int idx = e * 256 + tid;   // 0..2047 f32x4 slots (64 q x 32)
    int qloc = idx >> 5;
    int d4 = (idx & 31) * 4;
    int q = m0 + qloc;
    if (q < HWc) {
      f32x4 a = {0.f, 0.f, 0.f, 0.f};
      float l = 0.f;
#pragma unroll
      for (int s = 0; s < 4; ++s) {
        const size_t sbase = ((size_t)s * NT + tile) * 64 + qloc;
        f32x4 v = *(const f32x4*)&Oacc[sbase * 128 + d4];
#pragma unroll
        for (int r = 0; r < 4; ++r) a[r] += v[r];
        l += Lp[sbase];
      }
      float linv = 1.f / l;
      u16x4 o;
#pragma unroll
      for (int r = 0; r < 4; ++r) o[r] = f2bf(a[r] * linv);
      *(u16x4*)(O + (size_t)(t * HWc + q) * DIMc + h * 128 + d4) = o;
    }
  }
}

extern "C" void kernel_launch(void* const* d_in, const int* in_sizes, int n_in,
                              void* d_out, int out_size, void* d_ws, size_t ws_size,
                              hipStream_t stream) {
  const float* hs  = (const float*)d_in[0];
  const float* his = (const float*)d_in[1];
  const float* fc  = (const float*)d_in[2];
  const float* fs  = (const float*)d_in[3];
  const float* fch = (const float*)d_in[4];
  const float* fsh = (const float*)d_in[5];
  const int*   sel = (const int*)d_in[6];
  const float* Wq  = (const float*)d_in[7];
  const float* bq  = (const float*)d_in[8];
  const float* Wk  = (const float*)d_in[9];
  const float* bk  = (const float*)d_in[10];
  const float* Wv  = (const float*)d_in[11];
  const float* bv  = (const float*)d_in[12];
  const float* Wo  = (const float*)d_in[13];
  const float* bo  = (const float*)d_in[14];
  const float* gq  = (const float*)d_in[15];
  const float* gk  = (const float*)d_in[16];

  const int QT = 3120, KT = 12480, DIMc = 1536;
  // Live-through-attention buffers first; the bf16 staging buffers (dead once the
  // gemms have consumed them) are overlaid with the 79.2 MB f32 segment partials.
  u16* p = (u16*)d_ws;
  u16* qb  = p; p += (size_t)QT * DIMc;
  u16* kb2 = p; p += (size_t)KT * DIMc;
  u16* vt  = p; p += (size_t)DIMc * KT;   // V^T [1536][12480]
  u16* ab  = p; p += (size_t)QT * DIMc;
  u16* wob = p; p += (size_t)DIMc * DIMc;
  u16* scratch = p;
  u16* hsb = scratch;
  u16* hib = hsb + (size_t)QT * DIMc;
  u16* wqb = hib + (size_t)KT * DIMc;
  u16* wkb = wqb + (size_t)DIMc * DIMc;
  u16* wvb = wkb + (size_t)DIMc * DIMc;
  float* oaccb = (float*)scratch;                      // f32 [4][600][64][128]
  float* lpb   = oaccb + (size_t)4 * 600 * 64 * 128;   // f32 [4][600][64]

  cvt_bf16<<<dim3((QT * DIMc / 4 + 255) / 256), 256, 0, stream>>>(hs, hsb, QT * DIMc / 4);
  cvt_bf16<<<dim3((KT * DIMc / 4 + 255) / 256), 256, 0, stream>>>(his, hib, KT * DIMc / 4);
  cvt_w4<<<dim3(2304, 4), 256, 0, stream>>>(Wq, Wk, Wv, Wo, wqb, wkb, wvb, wob);

  gemm_v2<0><<<dim3(12, 25), 256, 0, stream>>>(hsb, wqb, bq, qb, QT, 0);
  gemm_v2<0><<<dim3(12, 98), 256, 0, stream>>>(hib, wkb, bk, kb2, KT, 0);
  gemm_v2<2><<<dim3(12, 98), 256, 0, stream>>>(hib, wvb, bv, vt, KT, KT);  // writes V^T

  const float qscale = (float)(0.08838834764831845 * 1.4426950408889634);
  norm_rope2<<<dim3(QT), 192, 0, stream>>>(qb, gq, fc, fs, qscale);
  norm_rope2<<<dim3(KT), 192, 0, stream>>>(kb2, gk, fch, fsh, 1.0f);

  // attn10 clobbers hsb/hib/wq/wk/wv (all dead by now); wob stays live for the final gemm.
  attn10<<<dim3(1248), 256, 0, stream>>>(qb, kb2, vt, sel, oaccb, lpb);
  attn_norm<<<dim3(600), 256, 0, stream>>>(oaccb, lpb, ab);

  gemm_v2<1><<<dim3(12, 25), 256, 0, stream>>>(ab, wob, bo, d_out, QT, 0);
}

// Round 7
// 562.262 us; speedup vs baseline: 1.4908x; 1.0347x over previous
//
#include <hip/hip_runtime.h>

typedef unsigned short u16;
typedef __attribute__((ext_vector_type(4))) unsigned short u16x4;
typedef __attribute__((ext_vector_type(8))) unsigned short u16x8;
typedef __attribute__((ext_vector_type(4))) short s16x4;
typedef __attribute__((ext_vector_type(4))) float f32x4;
typedef __attribute__((ext_vector_type(8))) __bf16 bf16x8;

__device__ __forceinline__ u16 f2bf(float f) {
  union { float f; unsigned int u; } v; v.f = f;
  unsigned int u = v.u;
  unsigned int r = (u + 0x7fffu + ((u >> 16) & 1u)) >> 16;
  return (u16)r;
}
__device__ __forceinline__ u16 f2bf_hw(float f) {  // RNE via HW convert
  return __builtin_bit_cast(u16, (__bf16)f);
}
__device__ __forceinline__ float bf2f(u16 h) {
  union { unsigned int u; float f; } v; v.u = ((unsigned int)h) << 16;
  return v.f;
}
__device__ __forceinline__ f32x4 mfma16(u16x8 a, u16x8 b, f32x4 c) {
  return __builtin_amdgcn_mfma_f32_16x16x32_bf16(
      __builtin_bit_cast(bf16x8, a), __builtin_bit_cast(bf16x8, b), c, 0, 0, 0);
}
// K=16 variant: A/B are 4 bf16 (2 VGPRs)
__device__ __forceinline__ f32x4 mfma16k16(u16x4 a, u16x4 b, f32x4 c) {
  return __builtin_amdgcn_mfma_f32_16x16x16bf16_1k(
      __builtin_bit_cast(s16x4, a), __builtin_bit_cast(s16x4, b), c, 0, 0, 0);
}
// async global->LDS, 16B per lane; LDS dest = wave-uniform base + lane*16
__device__ __forceinline__ void glds16(const void* g, void* l) {
  __builtin_amdgcn_global_load_lds((const __attribute__((address_space(1))) void*)g,
                                   (__attribute__((address_space(3))) void*)l, 16, 0, 0);
}
// bijective XCD-chunked remap: XCD x (= bid&7 empirically) owns a contiguous
// logical-tile range -> blocks sharing operand panels are L2-co-resident.
__device__ __forceinline__ int xcd_chunk(int bid, int nwg) {
  int xcd = bid & 7, idx = bid >> 3;
  int q = nwg >> 3, r = nwg & 7;
  int base = xcd < r ? xcd * (q + 1) : r * (q + 1) + (xcd - r) * q;
  return base + idx;
}

// ---------------- fused fp32 -> bf16 conversion (all 6 tensors, 1 launch) ----------
__global__ __launch_bounds__(256) void cvt_all(
    const float* __restrict__ hs, const float* __restrict__ his,
    const float* __restrict__ Wq, const float* __restrict__ Wk,
    const float* __restrict__ Wv, const float* __restrict__ Wo,
    u16* __restrict__ hsb, u16* __restrict__ hib,
    u16* __restrict__ wqb, u16* __restrict__ wkb,
    u16* __restrict__ wvb, u16* __restrict__ wob) {
  // f4-chunk boundaries (all /256 -> block-uniform branch)
  const int N0 = 1198080, N1 = 5990400, N2 = 6580224, N3 = 7170048, N4 = 7759872;
  int i = blockIdx.x * 256 + threadIdx.x;
  const float* s; u16* o; int base;
  if (i < N0)      { s = hs;  o = hsb; base = 0;  }
  else if (i < N1) { s = his; o = hib; base = N0; }
  else if (i < N2) { s = Wq;  o = wqb; base = N1; }
  else if (i < N3) { s = Wk;  o = wkb; base = N2; }
  else if (i < N4) { s = Wv;  o = wvb; base = N3; }
  else             { s = Wo;  o = wob; base = N4; }
  int j = i - base;
  float4 v = ((const float4*)s)[j];
  u16x4 r;
  r.x = f2bf(v.x); r.y = f2bf(v.y); r.z = f2bf(v.z); r.w = f2bf(v.w);
  ((u16x4*)o)[j] = r;
}

// ---------------- GEMM: C[M,1536] = A[M,1536] @ W[1536,1536]^T + bias ----------------
// 1D grid + XCD-chunked swizzle (same-row-panel blocks co-resident per XCD).
template <int OUT, int NBX>  // OUT: 0 = bf16, 1 = f32
__global__ __launch_bounds__(256, 2) void gemm_v2(
    const u16* __restrict__ A, const u16* __restrict__ W,
    const float* __restrict__ bias, void* __restrict__ Cp, int M) {
  const int K = 1536, N = 1536;
  __shared__ __align__(16) u16 gsm[17408];
  u16* As = gsm;
  u16* Bs = gsm + 8192;
  const int tid = threadIdx.x;
  const int lane = tid & 63, wid = tid >> 6;
  const int quad = lane >> 4, l15 = lane & 15;
  const int lg = xcd_chunk(blockIdx.x, gridDim.x);
  const int m0 = (lg / NBX) * 128, n0 = (lg % NBX) * 128;
  const int wm = (wid >> 1) * 64, wn = (wid & 1) * 64;
  f32x4 acc[4][4];
#pragma unroll
  for (int i = 0; i < 4; ++i)
#pragma unroll
    for (int j = 0; j < 4; ++j)
#pragma unroll
      for (int r = 0; r < 4; ++r) acc[i][j][r] = 0.f;

  const int r8 = lane >> 3, c8 = lane & 7;
  const int gch = c8 ^ r8;

  for (int k0 = 0; k0 < K; k0 += 64) {
#pragma unroll
    for (int inst = 0; inst < 4; ++inst) {
      int row = wid * 32 + inst * 8 + r8;
      glds16(A + ((size_t)(m0 + row) * K + k0 + gch * 8), As + (wid * 32 + inst * 8) * 64);
      glds16(W + ((size_t)(n0 + row) * K + k0 + gch * 8), Bs + (wid * 32 + inst * 8) * 64);
    }
    asm volatile("s_waitcnt vmcnt(0)" ::: "memory");
    __syncthreads();
#pragma unroll
    for (int ks = 0; ks < 2; ++ks) {
      u16x8 af[4], bfr[4];
#pragma unroll
      for (int i = 0; i < 4; ++i) {
        int row = wm + i * 16 + l15;
        af[i] = *(const u16x8*)&As[row * 64 + (((ks * 4 + quad) ^ (l15 & 7)) * 8)];
      }
#pragma unroll
      for (int j = 0; j < 4; ++j) {
        int row = wn + j * 16 + l15;
        bfr[j] = *(const u16x8*)&Bs[row * 64 + (((ks * 4 + quad) ^ (l15 & 7)) * 8)];
      }
#pragma unroll
      for (int i = 0; i < 4; ++i)
#pragma unroll
        for (int j = 0; j < 4; ++j) acc[i][j] = mfma16(af[i], bfr[j], acc[i][j]);
    }
    __syncthreads();
  }

#pragma unroll
  for (int i = 0; i < 4; ++i) {
    int row = m0 + wm + i * 16 + quad * 4;
#pragma unroll
    for (int j = 0; j < 4; ++j) {
      int col = n0 + wn + j * 16 + l15;
      float bc = bias[col];
#pragma unroll
      for (int r = 0; r < 4; ++r) {
        if (row + r < M) {
          float v = acc[i][j][r] + bc;
          if (OUT == 1)
            ((float*)Cp)[(size_t)(row + r) * N + col] = v;
          else
            ((u16*)Cp)[(size_t)(row + r) * N + col] = f2bf(v);
        }
      }
    }
  }
}

// ---------------- fused K+V projection GEMM (stacked [3072][1536] weights) ----------
// bx<12: K-proj -> bf16 kb2[M][1536]; bx>=12: V-proj -> transposed bf16 vt[1536][KT].
__global__ __launch_bounds__(256, 2) void gemm_kv(
    const u16* __restrict__ A, const u16* __restrict__ Wkv,
    const float* __restrict__ bk, const float* __restrict__ bv,
    u16* __restrict__ Ck, u16* __restrict__ Vt, int M, int ldt) {
  const int K = 1536, NBX = 24;
  __shared__ __align__(16) u16 gsm[17408];
  u16* As = gsm;
  u16* Bs = gsm + 8192;
  const int tid = threadIdx.x;
  const int lane = tid & 63, wid = tid >> 6;
  const int quad = lane >> 4, l15 = lane & 15;
  const int lg = xcd_chunk(blockIdx.x, gridDim.x);
  const int m0 = (lg / NBX) * 128, n0 = (lg % NBX) * 128;  // n0 in [0,3072)
  const int wm = (wid >> 1) * 64, wn = (wid & 1) * 64;
  f32x4 acc[4][4];
#pragma unroll
  for (int i = 0; i < 4; ++i)
#pragma unroll
    for (int j = 0; j < 4; ++j)
#pragma unroll
      for (int r = 0; r < 4; ++r) acc[i][j][r] = 0.f;

  const int r8 = lane >> 3, c8 = lane & 7;
  const int gch = c8 ^ r8;

  for (int k0 = 0; k0 < K; k0 += 64) {
#pragma unroll
    for (int inst = 0; inst < 4; ++inst) {
      int row = wid * 32 + inst * 8 + r8;
      glds16(A + ((size_t)(m0 + row) * K + k0 + gch * 8), As + (wid * 32 + inst * 8) * 64);
      glds16(Wkv + ((size_t)(n0 + row) * K + k0 + gch * 8), Bs + (wid * 32 + inst * 8) * 64);
    }
    asm volatile("s_waitcnt vmcnt(0)" ::: "memory");
    __syncthreads();
#pragma unroll
    for (int ks = 0; ks < 2; ++ks) {
      u16x8 af[4], bfr[4];
#pragma unroll
      for (int i = 0; i < 4; ++i) {
        int row = wm + i * 16 + l15;
        af[i] = *(const u16x8*)&As[row * 64 + (((ks * 4 + quad) ^ (l15 & 7)) * 8)];
      }
#pragma unroll
      for (int j = 0; j < 4; ++j) {
        int row = wn + j * 16 + l15;
        bfr[j] = *(const u16x8*)&Bs[row * 64 + (((ks * 4 + quad) ^ (l15 & 7)) * 8)];
      }
#pragma unroll
      for (int i = 0; i < 4; ++i)
#pragma unroll
        for (int j = 0; j < 4; ++j) acc[i][j] = mfma16(af[i], bfr[j], acc[i][j]);
    }
    __syncthreads();
  }

  if (n0 < 1536) {  // K-projection: plain bf16 store
#pragma unroll
    for (int i = 0; i < 4; ++i) {
      int row = m0 + wm + i * 16 + quad * 4;
#pragma unroll
      for (int j = 0; j < 4; ++j) {
        int col = n0 + wn + j * 16 + l15;
        float bc = bk[col];
#pragma unroll
        for (int r = 0; r < 4; ++r) {
          if (row + r < M)
            Ck[(size_t)(row + r) * 1536 + col] = f2bf(acc[i][j][r] + bc);
        }
      }
    }
  } else {  // V-projection: transposed store via LDS
    const int n0v = n0 - 1536;
    u16* Ct = gsm;  // [128 n][136]
#pragma unroll
    for (int i = 0; i < 4; ++i)
#pragma unroll
      for (int j = 0; j < 4; ++j) {
        int nloc = wn + j * 16 + l15;
        float bc = bv[n0v + nloc];
#pragma unroll
        for (int r = 0; r < 4; ++r) {
          int mloc = wm + i * 16 + quad * 4 + r;
          Ct[nloc * 136 + mloc] = f2bf(acc[i][j][r] + bc);
        }
      }
    __syncthreads();
    int n = tid >> 1, half = tid & 1;
#pragma unroll
    for (int e = 0; e < 8; ++e) {
      int mloc = half * 64 + e * 8;
      if (m0 + mloc < M) {
        u16x8 v = *(const u16x8*)&Ct[n * 136 + mloc];
        *(u16x8*)(Vt + (size_t)(n0v + n) * ldt + m0 + mloc) = v;
      }
    }
  }
}

// ---------------- fused RMSNorm + interleaved RoPE, in-place bf16 ----------------
__global__ __launch_bounds__(192) void norm_rope2(u16* __restrict__ X,
                                                  const float* __restrict__ g,
                                                  const float* __restrict__ fc,
                                                  const float* __restrict__ fs,
                                                  float oscale) {
  const int DIMc = 1536;
  int row = blockIdx.x;
  int tid = threadIdx.x;
  u16* xr = X + (size_t)row * DIMc + tid * 8;
  u16x8 v = *(const u16x8*)xr;
  float x[8];
  float ss = 0.f;
#pragma unroll
  for (int e = 0; e < 8; ++e) { x[e] = bf2f(v[e]); ss += x[e] * x[e]; }
#pragma unroll
  for (int m = 1; m < 64; m <<= 1) ss += __shfl_xor(ss, m);
  __shared__ float w3[3];
  if ((tid & 63) == 0) w3[tid >> 6] = ss;
  __syncthreads();
  float rs = rsqrtf((w3[0] + w3[1] + w3[2]) * (1.f / 1536.f) + 1e-5f);
  int dhb = (tid * 8) & 127;
  const float* fcr = fc + (size_t)row * 128 + dhb;
  const float* fsr = fs + (size_t)row * 128 + dhb;
  float4 c0 = *(const float4*)fcr, c1 = *(const float4*)(fcr + 4);
  float4 s0 = *(const float4*)fsr, s1 = *(const float4*)(fsr + 4);
  const float* gp = g + tid * 8;
  float4 g0 = *(const float4*)gp, g1 = *(const float4*)(gp + 4);
  float cosv[4] = {c0.x, c0.z, c1.x, c1.z};
  float sinv[4] = {s0.y, s0.w, s1.y, s1.w};
  float gv[8] = {g0.x, g0.y, g0.z, g0.w, g1.x, g1.y, g1.z, g1.w};
  u16x8 o;
#pragma unroll
  for (int p = 0; p < 4; ++p) {
    float a = x[2 * p] * rs * gv[2 * p];
    float b = x[2 * p + 1] * rs * gv[2 * p + 1];
    o[2 * p] = f2bf((a * cosv[p] - b * sinv[p]) * oscale);
    o[2 * p + 1] = f2bf((a * sinv[p] + b * cosv[p]) * oscale);
  }
  *(u16x8*)xr = o;
}

// ---------------- block-sparse attention v10: 128-q macro-tile, conflict-free V ------
__global__ __launch_bounds__(256, 3) void attn10(
    const u16* __restrict__ Q, const u16* __restrict__ Kb,
    const u16* __restrict__ VT, const int* __restrict__ sel,
    float* __restrict__ Oacc, float* __restrict__ Lp) {
  const int HWc = 1560, DIMc = 1536, KTt = 12480, NT = 600;
  __shared__ __align__(16) u16 smem[16384];  // Ks0|Ks1|Vt0|Vt1 (8 KB each)
  const int tid = threadIdx.x;
  const int lane = tid & 63, wid = tid >> 6;
  const int quad = lane >> 4, l15 = lane & 15;

  // XCD swizzle: all 52 blocks (4 segs x 13 macro-tiles) of one (h,t) on one XCD;
  int bid = blockIdx.x;
  int xcd = bid & 7, slot = bid >> 3;
  int g = xcd + 8 * (slot / 52);
  int within = slot % 52;
  int seg = within / 13;
  int mt = within % 13;
  const int m0 = mt * 128;
  const int h = g >> 1, t = g & 1;

  int s0v = sel[2 * t];
  const int b0 = s0v > 0 ? s0v : 0;
  const int b1 = sel[2 * t + 1];
  const int nk = (b1 >= 0) ? 2 * HWc : HWc;
  const int nch = (nk + 31) >> 5;
  const int cpseg = (nch + 3) >> 2;
  const int c0 = seg * cpseg;
  const int c1 = (c0 + cpseg < nch) ? c0 + cpseg : nch;

  // Q B-frags: this wave's 32 q rows (2 sub-tiles of 16)
  u16x8 qf[2][4];
#pragma unroll
  for (int qt = 0; qt < 2; ++qt) {
    int qrow = m0 + wid * 32 + qt * 16 + l15;
    if (qrow > HWc - 1) qrow = HWc - 1;
    const u16* qp = Q + (size_t)(t * HWc + qrow) * DIMc + h * 128;
#pragma unroll
    for (int ks = 0; ks < 4; ++ks) qf[qt][ks] = *(const u16x8*)(qp + ks * 32 + quad * 8);
  }

  f32x4 oacc[2][8];  // partial O^T: [q-subtile][d-tile]
#pragma unroll
  for (int qt = 0; qt < 2; ++qt)
#pragma unroll
    for (int m = 0; m < 8; ++m)
#pragma unroll
      for (int r = 0; r < 4; ++r) oacc[qt][m][r] = 0.f;
  float lp[2] = {0.f, 0.f};

  auto stage = [&](int kc, int buf) {
    u16* Ks = smem + buf * 4096;
    u16* Vt = smem + 8192 + buf * 4096;
#pragma unroll
    for (int n = 0; n < 2; ++n) {
      int kl = wid * 8 + n * 4 + (lane >> 4);
      int gc = (lane & 15) ^ (kl & 15);
      int kg = kc + kl;
      if (kg >= nk) kg = 0;
      int big = kg >= HWc;
      int tok = (big ? b1 : b0) * HWc + kg - (big ? HWc : 0);
      glds16(Kb + ((size_t)tok * DIMc + h * 128 + gc * 8), Ks + (wid * 8 + n * 4) * 128);
    }
#pragma unroll
    for (int n = 0; n < 2; ++n) {
      int dl = wid * 32 + n * 16 + (lane >> 2);
      int gc = (lane & 3) ^ (dl & 3) ^ ((dl >> 2) & 3);
      int tg = kc + gc * 8;
      if (tg >= nk) tg = 0;
      int big = tg >= HWc;
      int tok = (big ? b1 : b0) * HWc + tg - (big ? HWc : 0);
      glds16(VT + ((size_t)(h * 128 + dl) * KTt + tok), Vt + (wid * 32 + n * 16) * 32);
    }
  };

  if (c0 < c1) stage(c0 * 32, 0);

  for (int c = c0; c < c1; ++c) {
    const int buf = (c - c0) & 1;
    u16* Ks = smem + buf * 4096;
    u16* Vt = smem + 8192 + buf * 4096;
    asm volatile("s_waitcnt vmcnt(0)\n\ts_barrier" ::: "memory");
    if (c + 1 < c1) stage((c + 1) * 32, buf ^ 1);

    f32x4 s[2][2];  // [gg][qt]
#pragma unroll
    for (int gg = 0; gg < 2; ++gg)
#pragma unroll
      for (int qt = 0; qt < 2; ++qt)
#pragma unroll
        for (int r = 0; r < 4; ++r) s[gg][qt][r] = 0.f;
#pragma unroll
    for (int ks = 0; ks < 4; ++ks)
#pragma unroll
      for (int gg = 0; gg < 2; ++gg) {
        u16x8 ka = *(const u16x8*)&Ks[(gg * 16 + l15) * 128 + (((ks * 4 + quad) ^ l15) * 8)];
#pragma unroll
        for (int qt = 0; qt < 2; ++qt) s[gg][qt] = mfma16(ka, qf[qt][ks], s[gg][qt]);
      }

    float p[2][2][4];
#pragma unroll
    for (int gg = 0; gg < 2; ++gg)
#pragma unroll
      for (int qt = 0; qt < 2; ++qt)
#pragma unroll
        for (int r = 0; r < 4; ++r) p[gg][qt][r] = exp2f(s[gg][qt][r]);
    if ((c + 1) * 32 > nk) {  // wave-uniform
#pragma unroll
      for (int gg = 0; gg < 2; ++gg)
#pragma unroll
        for (int r = 0; r < 4; ++r) {
          bool bad = c * 32 + gg * 16 + quad * 4 + r >= nk;
          if (bad) {
#pragma unroll
            for (int qt = 0; qt < 2; ++qt) p[gg][qt][r] = 0.f;
          }
        }
    }
    u16x4 pb[2][2];
#pragma unroll
    for (int gg = 0; gg < 2; ++gg)
#pragma unroll
      for (int qt = 0; qt < 2; ++qt)
#pragma unroll
        for (int r = 0; r < 4; ++r) {
          lp[qt] += p[gg][qt][r];
          pb[gg][qt][r] = f2bf_hw(p[gg][qt][r]);
        }

#pragma unroll
    for (int m = 0; m < 8; ++m) {
      int d = m * 16 + l15;
#pragma unroll
      for (int gg = 0; gg < 2; ++gg) {
        int sl = (gg * 2 + (quad >> 1)) ^ (d & 3) ^ ((d >> 2) & 3);
        u16x4 va = *(const u16x4*)&Vt[d * 32 + sl * 8 + (quad & 1) * 4];
#pragma unroll
        for (int qt = 0; qt < 2; ++qt) oacc[qt][m] = mfma16k16(va, pb[gg][qt], oacc[qt][m]);
      }
    }
  }

#pragma unroll
  for (int qt = 0; qt < 2; ++qt) {
    lp[qt] += __shfl_xor(lp[qt], 16);
    lp[qt] += __shfl_xor(lp[qt], 32);
  }
#pragma unroll
  for (int qt = 0; qt < 2; ++qt) {
    int qrow0 = m0 + wid * 32 + qt * 16;  // wave-uniform
    if (qrow0 < HWc) {
      size_t sb = ((size_t)seg * NT + g * 25 + (qrow0 >> 6)) * 64 + (qrow0 & 63);
      if (lane < 16 && qrow0 + lane < HWc) Lp[sb + lane] = lp[qt];
      if (qrow0 + l15 < HWc) {
#pragma unroll
        for (int m = 0; m < 8; ++m)
          *(f32x4*)&Oacc[(sb + l15) * 128 + m * 16 + quad * 4] = oacc[qt][m];
      }
    }
  }
}

// ---------------- normalize: O = bf16(sum_seg Oacc / sum_seg Lp) ----------------
__global__ __launch_bounds__(256) void attn_norm(const float* __restrict__ Oacc,
                                                 const float* __restrict__ Lp,
                                                 u16* __restrict__ O) {
  const int HWc = 1560, DIMc = 1536, NT = 600;
  int tile = blockIdx.x;  // 600
  int g = tile / 25, mt = tile % 25;
  int h = g >> 1, t = g & 1;
  int m0 = mt * 64;
  int tid = threadIdx.x;
#pragma unroll
  for (int e = 0; e < 8; ++e) {
    int idx = e * 256 + tid;   // 0..2047 f32x4 slots (64 q x 32)
    int qloc = idx >> 5;
    int d4 = (idx & 31) * 4;
    int q = m0 + qloc;
    if (q < HWc) {
      f32x4 a = {0.f, 0.f, 0.f, 0.f};
      float l = 0.f;
#pragma unroll
      for (int s = 0; s < 4; ++s) {
        const size_t sbase = ((size_t)s * NT + tile) * 64 + qloc;
        f32x4 v = *(const f32x4*)&Oacc[sbase * 128 + d4];
#pragma unroll
        for (int r = 0; r < 4; ++r) a[r] += v[r];
        l += Lp[sbase];
      }
      float linv = 1.f / l;
      u16x4 o;
#pragma unroll
      for (int r = 0; r < 4; ++r) o[r] = f2bf(a[r] * linv);
      *(u16x4*)(O + (size_t)(t * HWc + q) * DIMc + h * 128 + d4) = o;
    }
  }
}

extern "C" void kernel_launch(void* const* d_in, const int* in_sizes, int n_in,
                              void* d_out, int out_size, void* d_ws, size_t ws_size,
                              hipStream_t stream) {
  const float* hs  = (const float*)d_in[0];
  const float* his = (const float*)d_in[1];
  const float* fc  = (const float*)d_in[2];
  const float* fs  = (const float*)d_in[3];
  const float* fch = (const float*)d_in[4];
  const float* fsh = (const float*)d_in[5];
  const int*   sel = (const int*)d_in[6];
  const float* Wq  = (const float*)d_in[7];
  const float* bq  = (const float*)d_in[8];
  const float* Wk  = (const float*)d_in[9];
  const float* bk  = (const float*)d_in[10];
  const float* Wv  = (const float*)d_in[11];
  const float* bv  = (const float*)d_in[12];
  const float* Wo  = (const float*)d_in[13];
  const float* bo  = (const float*)d_in[14];
  const float* gq  = (const float*)d_in[15];
  const float* gk  = (const float*)d_in[16];

  const int QT = 3120, KT = 12480, DIMc = 1536;
  // Live-through-attention buffers first; the bf16 staging buffers (dead once the
  // gemms have consumed them) are overlaid with the 79.2 MB f32 segment partials.
  u16* p = (u16*)d_ws;
  u16* qb  = p; p += (size_t)QT * DIMc;
  u16* kb2 = p; p += (size_t)KT * DIMc;
  u16* vt  = p; p += (size_t)DIMc * KT;   // V^T [1536][12480]
  u16* ab  = p; p += (size_t)QT * DIMc;
  u16* wob = p; p += (size_t)DIMc * DIMc;
  u16* scratch = p;
  u16* hsb = scratch;
  u16* hib = hsb + (size_t)QT * DIMc;
  u16* wqb = hib + (size_t)KT * DIMc;
  u16* wkb = wqb + (size_t)DIMc * DIMc;   // wkb and wvb adjacent -> stacked [3072][1536]
  u16* wvb = wkb + (size_t)DIMc * DIMc;
  float* oaccb = (float*)scratch;                      // f32 [4][600][64][128]
  float* lpb   = oaccb + (size_t)4 * 600 * 64 * 128;   // f32 [4][600][64]

  cvt_all<<<dim3(32616), 256, 0, stream>>>(hs, his, Wq, Wk, Wv, Wo,
                                           hsb, hib, wqb, wkb, wvb, wob);

  gemm_v2<0, 12><<<dim3(300), 256, 0, stream>>>(hsb, wqb, bq, qb, QT);
  gemm_kv<<<dim3(2352), 256, 0, stream>>>(hib, wkb, bk, bv, kb2, vt, KT, KT);

  const float qscale = (float)(0.08838834764831845 * 1.4426950408889634);
  norm_rope2<<<dim3(QT), 192, 0, stream>>>(qb, gq, fc, fs, qscale);
  norm_rope2<<<dim3(KT), 192, 0, stream>>>(kb2, gk, fch, fsh, 1.0f);

  // attn10 clobbers hsb/hib/wq/wk/wv (all dead by now); wob stays live for the final gemm.
  attn10<<<dim3(1248), 256, 0, stream>>>(qb, kb2, vt, sel, oaccb, lpb);
  attn_norm<<<dim3(600), 256, 0, stream>>>(oaccb, lpb, ab);

  gemm_v2<1, 12><<<dim3(300), 256, 0, stream>>>(ab, wob, bo, d_out, QT);
}

// Round 8
// 554.302 us; speedup vs baseline: 1.5122x; 1.0144x over previous
//
#include <hip/hip_runtime.h>

typedef unsigned short u16;
typedef __attribute__((ext_vector_type(4))) unsigned short u16x4;
typedef __attribute__((ext_vector_type(8))) unsigned short u16x8;
typedef __attribute__((ext_vector_type(4))) short s16x4;
typedef __attribute__((ext_vector_type(4))) float f32x4;
typedef __attribute__((ext_vector_type(8))) __bf16 bf16x8;

__device__ __forceinline__ u16 f2bf(float f) {
  union { float f; unsigned int u; } v; v.f = f;
  unsigned int u = v.u;
  unsigned int r = (u + 0x7fffu + ((u >> 16) & 1u)) >> 16;
  return (u16)r;
}
__device__ __forceinline__ u16 f2bf_hw(float f) {  // RNE via HW convert
  return __builtin_bit_cast(u16, (__bf16)f);
}
__device__ __forceinline__ float bf2f(u16 h) {
  union { unsigned int u; float f; } v; v.u = ((unsigned int)h) << 16;
  return v.f;
}
__device__ __forceinline__ f32x4 mfma16(u16x8 a, u16x8 b, f32x4 c) {
  return __builtin_amdgcn_mfma_f32_16x16x32_bf16(
      __builtin_bit_cast(bf16x8, a), __builtin_bit_cast(bf16x8, b), c, 0, 0, 0);
}
// K=16 variant: A/B are 4 bf16 (2 VGPRs)
__device__ __forceinline__ f32x4 mfma16k16(u16x4 a, u16x4 b, f32x4 c) {
  return __builtin_amdgcn_mfma_f32_16x16x16bf16_1k(
      __builtin_bit_cast(s16x4, a), __builtin_bit_cast(s16x4, b), c, 0, 0, 0);
}
// async global->LDS, 16B per lane; LDS dest = wave-uniform base + lane*16
__device__ __forceinline__ void glds16(const void* g, void* l) {
  __builtin_amdgcn_global_load_lds((const __attribute__((address_space(1))) void*)g,
                                   (__attribute__((address_space(3))) void*)l, 16, 0, 0);
}
// bijective XCD-chunked remap: XCD x (= bid&7 empirically) owns a contiguous
// logical-tile range -> blocks sharing operand panels are L2-co-resident.
__device__ __forceinline__ int xcd_chunk(int bid, int nwg) {
  int xcd = bid & 7, idx = bid >> 3;
  int q = nwg >> 3, r = nwg & 7;
  int base = xcd < r ? xcd * (q + 1) : r * (q + 1) + (xcd - r) * q;
  return base + idx;
}

// ---------------- fused fp32 -> bf16 conversion (all 6 tensors, 1 launch) ----------
__global__ __launch_bounds__(256) void cvt_all(
    const float* __restrict__ hs, const float* __restrict__ his,
    const float* __restrict__ Wq, const float* __restrict__ Wk,
    const float* __restrict__ Wv, const float* __restrict__ Wo,
    u16* __restrict__ hsb, u16* __restrict__ hib,
    u16* __restrict__ wqb, u16* __restrict__ wkb,
    u16* __restrict__ wvb, u16* __restrict__ wob) {
  // f4-chunk boundaries (all /256 -> block-uniform branch)
  const int N0 = 1198080, N1 = 5990400, N2 = 6580224, N3 = 7170048, N4 = 7759872;
  int i = blockIdx.x * 256 + threadIdx.x;
  const float* s; u16* o; int base;
  if (i < N0)      { s = hs;  o = hsb; base = 0;  }
  else if (i < N1) { s = his; o = hib; base = N0; }
  else if (i < N2) { s = Wq;  o = wqb; base = N1; }
  else if (i < N3) { s = Wk;  o = wkb; base = N2; }
  else if (i < N4) { s = Wv;  o = wvb; base = N3; }
  else             { s = Wo;  o = wob; base = N4; }
  int j = i - base;
  float4 v = ((const float4*)s)[j];
  u16x4 r;
  r.x = f2bf(v.x); r.y = f2bf(v.y); r.z = f2bf(v.z); r.w = f2bf(v.w);
  ((u16x4*)o)[j] = r;
}

// ---------------- GEMM: C[M,1536] = A[M,1536] @ W[1536,1536]^T + bias ----------------
// 1D grid + XCD-chunked swizzle (same-row-panel blocks co-resident per XCD).
template <int OUT, int NBX>  // OUT: 0 = bf16, 1 = f32
__global__ __launch_bounds__(256, 2) void gemm_v2(
    const u16* __restrict__ A, const u16* __restrict__ W,
    const float* __restrict__ bias, void* __restrict__ Cp, int M) {
  const int K = 1536, N = 1536;
  __shared__ __align__(16) u16 gsm[17408];
  u16* As = gsm;
  u16* Bs = gsm + 8192;
  const int tid = threadIdx.x;
  const int lane = tid & 63, wid = tid >> 6;
  const int quad = lane >> 4, l15 = lane & 15;
  const int lg = xcd_chunk(blockIdx.x, gridDim.x);
  const int m0 = (lg / NBX) * 128, n0 = (lg % NBX) * 128;
  const int wm = (wid >> 1) * 64, wn = (wid & 1) * 64;
  f32x4 acc[4][4];
#pragma unroll
  for (int i = 0; i < 4; ++i)
#pragma unroll
    for (int j = 0; j < 4; ++j)
#pragma unroll
      for (int r = 0; r < 4; ++r) acc[i][j][r] = 0.f;

  const int r8 = lane >> 3, c8 = lane & 7;
  const int gch = c8 ^ r8;

  for (int k0 = 0; k0 < K; k0 += 64) {
#pragma unroll
    for (int inst = 0; inst < 4; ++inst) {
      int row = wid * 32 + inst * 8 + r8;
      glds16(A + ((size_t)(m0 + row) * K + k0 + gch * 8), As + (wid * 32 + inst * 8) * 64);
      glds16(W + ((size_t)(n0 + row) * K + k0 + gch * 8), Bs + (wid * 32 + inst * 8) * 64);
    }
    asm volatile("s_waitcnt vmcnt(0)" ::: "memory");
    __syncthreads();
#pragma unroll
    for (int ks = 0; ks < 2; ++ks) {
      u16x8 af[4], bfr[4];
#pragma unroll
      for (int i = 0; i < 4; ++i) {
        int row = wm + i * 16 + l15;
        af[i] = *(const u16x8*)&As[row * 64 + (((ks * 4 + quad) ^ (l15 & 7)) * 8)];
      }
#pragma unroll
      for (int j = 0; j < 4; ++j) {
        int row = wn + j * 16 + l15;
        bfr[j] = *(const u16x8*)&Bs[row * 64 + (((ks * 4 + quad) ^ (l15 & 7)) * 8)];
      }
#pragma unroll
      for (int i = 0; i < 4; ++i)
#pragma unroll
        for (int j = 0; j < 4; ++j) acc[i][j] = mfma16(af[i], bfr[j], acc[i][j]);
    }
    __syncthreads();
  }

#pragma unroll
  for (int i = 0; i < 4; ++i) {
    int row = m0 + wm + i * 16 + quad * 4;
#pragma unroll
    for (int j = 0; j < 4; ++j) {
      int col = n0 + wn + j * 16 + l15;
      float bc = bias[col];
#pragma unroll
      for (int r = 0; r < 4; ++r) {
        if (row + r < M) {
          float v = acc[i][j][r] + bc;
          if (OUT == 1)
            ((float*)Cp)[(size_t)(row + r) * N + col] = v;
          else
            ((u16*)Cp)[(size_t)(row + r) * N + col] = f2bf(v);
        }
      }
    }
  }
}

// ---------------- fused K+V projection GEMM (stacked [3072][1536] weights) ----------
// n-quartered XCD ordering: lg -> (qtr = lg/588, m = (lg%588)/6, n = qtr*6 + lg%6).
// Each XCD owns 49 m-panels x 6 n-panels: W slice 2.36 MB stays L2-resident while
// A streams once per quarter (A fetch 4x38 MB vs measured 305 MB with n-fastest).
__global__ __launch_bounds__(256, 2) void gemm_kv(
    const u16* __restrict__ A, const u16* __restrict__ Wkv,
    const float* __restrict__ bk, const float* __restrict__ bv,
    u16* __restrict__ Ck, u16* __restrict__ Vt, int M, int ldt) {
  const int K = 1536;
  __shared__ __align__(16) u16 gsm[17408];
  u16* As = gsm;
  u16* Bs = gsm + 8192;
  const int tid = threadIdx.x;
  const int lane = tid & 63, wid = tid >> 6;
  const int quad = lane >> 4, l15 = lane & 15;
  const int lg = xcd_chunk(blockIdx.x, gridDim.x);
  const int qtr = lg / 588;       // 588 = 98 m x 6 n
  const int rem = lg % 588;
  const int m0 = (rem / 6) * 128;
  const int n0 = (qtr * 6 + rem % 6) * 128;  // 0..2944
  const int wm = (wid >> 1) * 64, wn = (wid & 1) * 64;
  f32x4 acc[4][4];
#pragma unroll
  for (int i = 0; i < 4; ++i)
#pragma unroll
    for (int j = 0; j < 4; ++j)
#pragma unroll
      for (int r = 0; r < 4; ++r) acc[i][j][r] = 0.f;

  const int r8 = lane >> 3, c8 = lane & 7;
  const int gch = c8 ^ r8;

  for (int k0 = 0; k0 < K; k0 += 64) {
#pragma unroll
    for (int inst = 0; inst < 4; ++inst) {
      int row = wid * 32 + inst * 8 + r8;
      glds16(A + ((size_t)(m0 + row) * K + k0 + gch * 8), As + (wid * 32 + inst * 8) * 64);
      glds16(Wkv + ((size_t)(n0 + row) * K + k0 + gch * 8), Bs + (wid * 32 + inst * 8) * 64);
    }
    asm volatile("s_waitcnt vmcnt(0)" ::: "memory");
    __syncthreads();
#pragma unroll
    for (int ks = 0; ks < 2; ++ks) {
      u16x8 af[4], bfr[4];
#pragma unroll
      for (int i = 0; i < 4; ++i) {
        int row = wm + i * 16 + l15;
        af[i] = *(const u16x8*)&As[row * 64 + (((ks * 4 + quad) ^ (l15 & 7)) * 8)];
      }
#pragma unroll
      for (int j = 0; j < 4; ++j) {
        int row = wn + j * 16 + l15;
        bfr[j] = *(const u16x8*)&Bs[row * 64 + (((ks * 4 + quad) ^ (l15 & 7)) * 8)];
      }
#pragma unroll
      for (int i = 0; i < 4; ++i)
#pragma unroll
        for (int j = 0; j < 4; ++j) acc[i][j] = mfma16(af[i], bfr[j], acc[i][j]);
    }
    __syncthreads();
  }

  if (n0 < 1536) {  // K-projection: plain bf16 store
#pragma unroll
    for (int i = 0; i < 4; ++i) {
      int row = m0 + wm + i * 16 + quad * 4;
#pragma unroll
      for (int j = 0; j < 4; ++j) {
        int col = n0 + wn + j * 16 + l15;
        float bc = bk[col];
#pragma unroll
        for (int r = 0; r < 4; ++r) {
          if (row + r < M)
            Ck[(size_t)(row + r) * 1536 + col] = f2bf(acc[i][j][r] + bc);
        }
      }
    }
  } else {  // V-projection: transposed store via LDS
    const int n0v = n0 - 1536;
    u16* Ct = gsm;  // [128 n][136]
#pragma unroll
    for (int i = 0; i < 4; ++i)
#pragma unroll
      for (int j = 0; j < 4; ++j) {
        int nloc = wn + j * 16 + l15;
        float bc = bv[n0v + nloc];
#pragma unroll
        for (int r = 0; r < 4; ++r) {
          int mloc = wm + i * 16 + quad * 4 + r;
          Ct[nloc * 136 + mloc] = f2bf(acc[i][j][r] + bc);
        }
      }
    __syncthreads();
    int n = tid >> 1, half = tid & 1;
#pragma unroll
    for (int e = 0; e < 8; ++e) {
      int mloc = half * 64 + e * 8;
      if (m0 + mloc < M) {
        u16x8 v = *(const u16x8*)&Ct[n * 136 + mloc];
        *(u16x8*)(Vt + (size_t)(n0v + n) * ldt + m0 + mloc) = v;
      }
    }
  }
}

// ---------------- fused RMSNorm + interleaved RoPE, in-place bf16 ----------------
__global__ __launch_bounds__(192) void norm_rope2(u16* __restrict__ X,
                                                  const float* __restrict__ g,
                                                  const float* __restrict__ fc,
                                                  const float* __restrict__ fs,
                                                  float oscale) {
  const int DIMc = 1536;
  int row = blockIdx.x;
  int tid = threadIdx.x;
  u16* xr = X + (size_t)row * DIMc + tid * 8;
  u16x8 v = *(const u16x8*)xr;
  float x[8];
  float ss = 0.f;
#pragma unroll
  for (int e = 0; e < 8; ++e) { x[e] = bf2f(v[e]); ss += x[e] * x[e]; }
#pragma unroll
  for (int m = 1; m < 64; m <<= 1) ss += __shfl_xor(ss, m);
  __shared__ float w3[3];
  if ((tid & 63) == 0) w3[tid >> 6] = ss;
  __syncthreads();
  float rs = rsqrtf((w3[0] + w3[1] + w3[2]) * (1.f / 1536.f) + 1e-5f);
  int dhb = (tid * 8) & 127;
  const float* fcr = fc + (size_t)row * 128 + dhb;
  const float* fsr = fs + (size_t)row * 128 + dhb;
  float4 c0 = *(const float4*)fcr, c1 = *(const float4*)(fcr + 4);
  float4 s0 = *(const float4*)fsr, s1 = *(const float4*)(fsr + 4);
  const float* gp = g + tid * 8;
  float4 g0 = *(const float4*)gp, g1 = *(const float4*)(gp + 4);
  float cosv[4] = {c0.x, c0.z, c1.x, c1.z};
  float sinv[4] = {s0.y, s0.w, s1.y, s1.w};
  float gv[8] = {g0.x, g0.y, g0.z, g0.w, g1.x, g1.y, g1.z, g1.w};
  u16x8 o;
#pragma unroll
  for (int p = 0; p < 4; ++p) {
    float a = x[2 * p] * rs * gv[2 * p];
    float b = x[2 * p + 1] * rs * gv[2 * p + 1];
    o[2 * p] = f2bf((a * cosv[p] - b * sinv[p]) * oscale);
    o[2 * p + 1] = f2bf((a * sinv[p] + b * cosv[p]) * oscale);
  }
  *(u16x8*)xr = o;
}

// ---------------- block-sparse attention v11: t-balanced XCD map ----------------
// Same compute core as v10. New block decode: unit = (h,seg,t) spread so each XCD
// hosts 6 u-slots x both t (identical workload even when one t has half the keys;
// v10 pinned t = xcd&1 -> half the XCDs idled at half-time, occupancy 19.8%).
__global__ __launch_bounds__(256, 3) void attn11(
    const u16* __restrict__ Q, const u16* __restrict__ Kb,
    const u16* __restrict__ VT, const int* __restrict__ sel,
    float* __restrict__ Oacc, float* __restrict__ Lp) {
  const int HWc = 1560, DIMc = 1536, KTt = 12480, NT = 600;
  __shared__ __align__(16) u16 smem[16384];  // Ks0|Ks1|Vt0|Vt1 (8 KB each)
  const int tid = threadIdx.x;
  const int lane = tid & 63, wid = tid >> 6;
  const int quad = lane >> 4, l15 = lane & 15;

  // balanced decode: bid -> (xcd, idx); il = idx/13 in 0..11, mt = idx%13.
  // u = xcd + 8*(il>>1) in 0..47 -> seg = u/12 (multiset {0,0,1,2,2,3} per XCD),
  // h = u%12; t = il&1 (both t on every XCD). 13 mt-blocks of a unit stay
  // bid-contiguous on their XCD -> K/V slice L2 sharing preserved.
  int bid = blockIdx.x;
  int xcd = bid & 7, idx = bid >> 3;
  int il = idx / 13, mt = idx % 13;
  int u = xcd + 8 * (il >> 1);
  const int t = il & 1;
  const int seg = u / 12;
  const int h = u % 12;
  const int m0 = mt * 128;
  const int g = h * 2 + t;

  int s0v = sel[2 * t];
  const int b0 = s0v > 0 ? s0v : 0;
  const int b1 = sel[2 * t + 1];
  const int nk = (b1 >= 0) ? 2 * HWc : HWc;
  const int nch = (nk + 31) >> 5;
  const int cpseg = (nch + 3) >> 2;
  const int c0 = seg * cpseg;
  const int c1 = (c0 + cpseg < nch) ? c0 + cpseg : nch;

  // Q B-frags: this wave's 32 q rows (2 sub-tiles of 16)
  u16x8 qf[2][4];
#pragma unroll
  for (int qt = 0; qt < 2; ++qt) {
    int qrow = m0 + wid * 32 + qt * 16 + l15;
    if (qrow > HWc - 1) qrow = HWc - 1;
    const u16* qp = Q + (size_t)(t * HWc + qrow) * DIMc + h * 128;
#pragma unroll
    for (int ks = 0; ks < 4; ++ks) qf[qt][ks] = *(const u16x8*)(qp + ks * 32 + quad * 8);
  }

  f32x4 oacc[2][8];  // partial O^T: [q-subtile][d-tile]
#pragma unroll
  for (int qt = 0; qt < 2; ++qt)
#pragma unroll
    for (int m = 0; m < 8; ++m)
#pragma unroll
      for (int r = 0; r < 4; ++r) oacc[qt][m][r] = 0.f;
  float lp[2] = {0.f, 0.f};

  auto stage = [&](int kc, int buf) {
    u16* Ks = smem + buf * 4096;
    u16* Vt = smem + 8192 + buf * 4096;
#pragma unroll
    for (int n = 0; n < 2; ++n) {
      int kl = wid * 8 + n * 4 + (lane >> 4);
      int gc = (lane & 15) ^ (kl & 15);
      int kg = kc + kl;
      if (kg >= nk) kg = 0;
      int big = kg >= HWc;
      int tok = (big ? b1 : b0) * HWc + kg - (big ? HWc : 0);
      glds16(Kb + ((size_t)tok * DIMc + h * 128 + gc * 8), Ks + (wid * 8 + n * 4) * 128);
    }
#pragma unroll
    for (int n = 0; n < 2; ++n) {
      int dl = wid * 32 + n * 16 + (lane >> 2);
      int gc = (lane & 3) ^ (dl & 3) ^ ((dl >> 2) & 3);
      int tg = kc + gc * 8;
      if (tg >= nk) tg = 0;
      int big = tg >= HWc;
      int tok = (big ? b1 : b0) * HWc + tg - (big ? HWc : 0);
      glds16(VT + ((size_t)(h * 128 + dl) * KTt + tok), Vt + (wid * 32 + n * 16) * 32);
    }
  };

  if (c0 < c1) stage(c0 * 32, 0);

  for (int c = c0; c < c1; ++c) {
    const int buf = (c - c0) & 1;
    u16* Ks = smem + buf * 4096;
    u16* Vt = smem + 8192 + buf * 4096;
    asm volatile("s_waitcnt vmcnt(0)\n\ts_barrier" ::: "memory");
    if (c + 1 < c1) stage((c + 1) * 32, buf ^ 1);

    f32x4 s[2][2];  // [gg][qt]
#pragma unroll
    for (int gg = 0; gg < 2; ++gg)
#pragma unroll
      for (int qt = 0; qt < 2; ++qt)
#pragma unroll
        for (int r = 0; r < 4; ++r) s[gg][qt][r] = 0.f;
#pragma unroll
    for (int ks = 0; ks < 4; ++ks)
#pragma unroll
      for (int gg = 0; gg < 2; ++gg) {
        u16x8 ka = *(const u16x8*)&Ks[(gg * 16 + l15) * 128 + (((ks * 4 + quad) ^ l15) * 8)];
#pragma unroll
        for (int qt = 0; qt < 2; ++qt) s[gg][qt] = mfma16(ka, qf[qt][ks], s[gg][qt]);
      }

    float p[2][2][4];
#pragma unroll
    for (int gg = 0; gg < 2; ++gg)
#pragma unroll
      for (int qt = 0; qt < 2; ++qt)
#pragma unroll
        for (int r = 0; r < 4; ++r) p[gg][qt][r] = exp2f(s[gg][qt][r]);
    if ((c + 1) * 32 > nk) {  // wave-uniform
#pragma unroll
      for (int gg = 0; gg < 2; ++gg)
#pragma unroll
        for (int r = 0; r < 4; ++r) {
          bool bad = c * 32 + gg * 16 + quad * 4 + r >= nk;
          if (bad) {
#pragma unroll
            for (int qt = 0; qt < 2; ++qt) p[gg][qt][r] = 0.f;
          }
        }
    }
    u16x4 pb[2][2];
#pragma unroll
    for (int gg = 0; gg < 2; ++gg)
#pragma unroll
      for (int qt = 0; qt < 2; ++qt)
#pragma unroll
        for (int r = 0; r < 4; ++r) {
          lp[qt] += p[gg][qt][r];
          pb[gg][qt][r] = f2bf_hw(p[gg][qt][r]);
        }

#pragma unroll
    for (int m = 0; m < 8; ++m) {
      int d = m * 16 + l15;
#pragma unroll
      for (int gg = 0; gg < 2; ++gg) {
        int sl = (gg * 2 + (quad >> 1)) ^ (d & 3) ^ ((d >> 2) & 3);
        u16x4 va = *(const u16x4*)&Vt[d * 32 + sl * 8 + (quad & 1) * 4];
#pragma unroll
        for (int qt = 0; qt < 2; ++qt) oacc[qt][m] = mfma16k16(va, pb[gg][qt], oacc[qt][m]);
      }
    }
  }

#pragma unroll
  for (int qt = 0; qt < 2; ++qt) {
    lp[qt] += __shfl_xor(lp[qt], 16);
    lp[qt] += __shfl_xor(lp[qt], 32);
  }
#pragma unroll
  for (int qt = 0; qt < 2; ++qt) {
    int qrow0 = m0 + wid * 32 + qt * 16;  // wave-uniform
    if (qrow0 < HWc) {
      size_t sb = ((size_t)seg * NT + g * 25 + (qrow0 >> 6)) * 64 + (qrow0 & 63);
      if (lane < 16 && qrow0 + lane < HWc) Lp[sb + lane] = lp[qt];
      if (qrow0 + l15 < HWc) {
#pragma unroll
        for (int m = 0; m < 8; ++m)
          *(f32x4*)&Oacc[(sb + l15) * 128 + m * 16 + quad * 4] = oacc[qt][m];
      }
    }
  }
}

// ---------------- normalize: O = bf16(sum_seg Oacc / sum_seg Lp) ----------------
__global__ __launch_bounds__(256) void attn_norm(const float* __restrict__ Oacc,
                                                 const float* __restrict__ Lp,
                                                 u16* __restrict__ O) {
  const int HWc = 1560, DIMc = 1536, NT = 600;
  int tile = blockIdx.x;  // 600
  int g = tile / 25, mt = tile % 25;
  int h = g >> 1, t = g & 1;
  int m0 = mt * 64;
  int tid = threadIdx.x;
#pragma unroll
  for (int e = 0; e < 8; ++e) {
    int idx = e * 256 + tid;   // 0..2047 f32x4 slots (64 q x 32)
    int qloc = idx >> 5;
    int d4 = (idx & 31) * 4;
    int q = m0 + qloc;
    if (q < HWc) {
      f32x4 a = {0.f, 0.f, 0.f, 0.f};
      float l = 0.f;
#pragma unroll
      for (int s = 0; s < 4; ++s) {
        const size_t sbase = ((size_t)s * NT + tile) * 64 + qloc;
        f32x4 v = *(const f32x4*)&Oacc[sbase * 128 + d4];
#pragma unroll
        for (int r = 0; r < 4; ++r) a[r] += v[r];
        l += Lp[sbase];
      }
      float linv = 1.f / l;
      u16x4 o;
#pragma unroll
      for (int r = 0; r < 4; ++r) o[r] = f2bf(a[r] * linv);
      *(u16x4*)(O + (size_t)(t * HWc + q) * DIMc + h * 128 + d4) = o;
    }
  }
}

extern "C" void kernel_launch(void* const* d_in, const int* in_sizes, int n_in,
                              void* d_out, int out_size, void* d_ws, size_t ws_size,
                              hipStream_t stream) {
  const float* hs  = (const float*)d_in[0];
  const float* his = (const float*)d_in[1];
  const float* fc  = (const float*)d_in[2];
  const float* fs  = (const float*)d_in[3];
  const float* fch = (const float*)d_in[4];
  const float* fsh = (const float*)d_in[5];
  const int*   sel = (const int*)d_in[6];
  const float* Wq  = (const float*)d_in[7];
  const float* bq  = (const float*)d_in[8];
  const float* Wk  = (const float*)d_in[9];
  const float* bk  = (const float*)d_in[10];
  const float* Wv  = (const float*)d_in[11];
  const float* bv  = (const float*)d_in[12];
  const float* Wo  = (const float*)d_in[13];
  const float* bo  = (const float*)d_in[14];
  const float* gq  = (const float*)d_in[15];
  const float* gk  = (const float*)d_in[16];

  const int QT = 3120, KT = 12480, DIMc = 1536;
  // Live-through-attention buffers first; the bf16 staging buffers (dead once the
  // gemms have consumed them) are overlaid with the 79.2 MB f32 segment partials.
  u16* p = (u16*)d_ws;
  u16* qb  = p; p += (size_t)QT * DIMc;
  u16* kb2 = p; p += (size_t)KT * DIMc;
  u16* vt  = p; p += (size_t)DIMc * KT;   // V^T [1536][12480]
  u16* ab  = p; p += (size_t)QT * DIMc;
  u16* wob = p; p += (size_t)DIMc * DIMc;
  u16* scratch = p;
  u16* hsb = scratch;
  u16* hib = hsb + (size_t)QT * DIMc;
  u16* wqb = hib + (size_t)KT * DIMc;
  u16* wkb = wqb + (size_t)DIMc * DIMc;   // wkb and wvb adjacent -> stacked [3072][1536]
  u16* wvb = wkb + (size_t)DIMc * DIMc;
  float* oaccb = (float*)scratch;                      // f32 [4][600][64][128]
  float* lpb   = oaccb + (size_t)4 * 600 * 64 * 128;   // f32 [4][600][64]

  cvt_all<<<dim3(32616), 256, 0, stream>>>(hs, his, Wq, Wk, Wv, Wo,
                                           hsb, hib, wqb, wkb, wvb, wob);

  gemm_v2<0, 12><<<dim3(300), 256, 0, stream>>>(hsb, wqb, bq, qb, QT);
  gemm_kv<<<dim3(2352), 256, 0, stream>>>(hib, wkb, bk, bv, kb2, vt, KT, KT);

  const float qscale = (float)(0.08838834764831845 * 1.4426950408889634);
  norm_rope2<<<dim3(QT), 192, 0, stream>>>(qb, gq, fc, fs, qscale);
  norm_rope2<<<dim3(KT), 192, 0, stream>>>(kb2, gk, fch, fsh, 1.0f);

  // attn11 clobbers hsb/hib/wq/wk/wv (all dead by now); wob stays live for the final gemm.
  attn11<<<dim3(1248), 256, 0, stream>>>(qb, kb2, vt, sel, oaccb, lpb);
  attn_norm<<<dim3(600), 256, 0, stream>>>(oaccb, lpb, ab);

  gemm_v2<1, 12><<<dim3(300), 256, 0, stream>>>(ab, wob, bo, d_out, QT);
}